// Round 12
// baseline (448.120 us; speedup 1.0000x reference)
//
#include <hip/hip_runtime.h>

#define NS 131072
#define KC 8
typedef unsigned long long u64;

#define LD4(P) (*reinterpret_cast<const float4*>(&sm[(P)]))
#define ST4(P) (*reinterpret_cast<float4*>(&sm[(P)]))
#define GL4(P) (*reinterpret_cast<const float4*>(&(P)))

#define FMA4(ACCR, AV, B) do { \
  ACCR[0]=fmaf((AV),(B).x,ACCR[0]); ACCR[1]=fmaf((AV),(B).y,ACCR[1]); \
  ACCR[2]=fmaf((AV),(B).z,ACCR[2]); ACCR[3]=fmaf((AV),(B).w,ACCR[3]); } while(0)

// 4-wide K step, 8 samples (rows st+8m) x 4 outputs (cols job..job+3).
#define K4(ACC, ABASE, ASTR, AK, BBASE, BSTR, JOFF, BK) do { \
  const float4 b0=LD4((BBASE)+((BK)*4+0)*(BSTR)+(JOFF)); \
  const float4 b1=LD4((BBASE)+((BK)*4+1)*(BSTR)+(JOFF)); \
  const float4 b2=LD4((BBASE)+((BK)*4+2)*(BSTR)+(JOFF)); \
  const float4 b3=LD4((BBASE)+((BK)*4+3)*(BSTR)+(JOFF)); \
  _Pragma("unroll") \
  for (int m_ = 0; m_ < 8; ++m_) { \
    const float4 av = LD4((ABASE)+(st+8*m_)*(ASTR)+(AK)*4); \
    FMA4(ACC[m_], av.x, b0); FMA4(ACC[m_], av.y, b1); \
    FMA4(ACC[m_], av.z, b2); FMA4(ACC[m_], av.w, b3); } \
} while(0)

#define INIT84(ACC, BPTR, OFF) do { \
  const float4 u_ = *reinterpret_cast<const float4*>(&(BPTR)[(OFF)]); \
  _Pragma("unroll") for (int m_=0;m_<8;++m_){ \
    ACC[m_][0]=u_.x; ACC[m_][1]=u_.y; ACC[m_][2]=u_.z; ACC[m_][3]=u_.w; } } while(0)

#define RELU84(ACC) do { _Pragma("unroll") for (int m_=0;m_<8;++m_) \
  { _Pragma("unroll") for (int j_=0;j_<4;++j_) ACC[m_][j_]=fmaxf(ACC[m_][j_],0.f); } } while(0)

// write 8x4 reg tile into e-arena rows (stride 68), cols job..job+3
#define WRITE_E(ACC) do { _Pragma("unroll") for (int m_=0;m_<8;++m_){ \
  ST4(EA + (st+8*m_)*68 + job) = \
    make_float4(ACC[m_][0],ACC[m_][1],ACC[m_][2],ACC[m_][3]); } } while(0)

// staged registers -> LDS: x [64][20], W [16][68] (8 floats each per thread)
#define STAGE_X() do { \
  ST4(AR + xr0*20 + xcc)     = rx0; \
  ST4(AR + xr0*20 + xcc + 4) = rx1; } while(0)
#define STAGE_W() do { \
  ST4(WB + wr*68 + wcc)     = rw0; \
  ST4(WB + wr*68 + wcc + 4) = rw1; } while(0)

// ---------------------------------------------------------------------------
// Block = 64 samples x 128 threads (2 waves). thread = (st = t>>4 in 0..7:
// 8 rows st+8m; ot = t&15: 4 cols job=ot*4). 5 blocks/CU (27.9KB LDS) ->
// 5 independent barrier domains hide staging latency.
// Arena (words): AR [0,1280) staging [64][20] -> z/d; EA [1280,5632)
// e1/e2 [64][68]; WB [5632,6720) weight chunks [16][68] / W3 [64][16];
// WD1i [6720,6976) Wd1. 6976 w = 27904 B.
// ---------------------------------------------------------------------------
#define AR   0
#define EA   1280
#define WB   5632
#define WD1i 6720
#define SMW  6976

__global__ __launch_bounds__(128, 2) void k_enc(
    const float* __restrict__ x,
    const float* __restrict__ We1, const float* __restrict__ be1,
    const float* __restrict__ We2, const float* __restrict__ be2,
    const float* __restrict__ We3, const float* __restrict__ be3,
    const float* __restrict__ Wd1, const float* __restrict__ bd1,
    const float* __restrict__ Wd2, const float* __restrict__ bd2,
    const float* __restrict__ centers,
    float* __restrict__ out_z, float* __restrict__ out_q,
    float* __restrict__ xhat, float* __restrict__ rec, float* __restrict__ kld,
    int* __restrict__ cidx, int* __restrict__ counts)
{
    __shared__ float sm[SMW];
    const int t  = threadIdx.x;
    const int ot = t & 15, st = t >> 4;
    const int job = ot * 4;
    const int s0 = blockIdx.x * 64;
    const int xr0 = t >> 1, xcc = (t & 1) * 8;     // x-staging: row, col8
    const int wr  = t >> 3, wcc = (t & 7) * 8;     // W-staging: row, col8

    // ================= L1: K=128, 8 chunks of 16, 1-deep prefetch ==========
    {
        float acc1[8][4];
        INIT84(acc1, be1, job);
        float4 rx0 = GL4(x[(size_t)(s0+xr0)*128 + xcc]);
        float4 rx1 = GL4(x[(size_t)(s0+xr0)*128 + xcc + 4]);
        float4 rw0 = GL4(We1[(size_t)wr*64 + wcc]);
        float4 rw1 = GL4(We1[(size_t)wr*64 + wcc + 4]);
        #pragma unroll 1
        for (int c = 0; c < 8; ++c) {
            __syncthreads();                      // prev chunk reads done
            STAGE_X(); STAGE_W();
            __syncthreads();                      // staging visible
            if (c < 7) {
                rx0 = GL4(x[(size_t)(s0+xr0)*128 + (c+1)*16 + xcc]);
                rx1 = GL4(x[(size_t)(s0+xr0)*128 + (c+1)*16 + xcc + 4]);
                rw0 = GL4(We1[(size_t)((c+1)*16 + wr)*64 + wcc]);
                rw1 = GL4(We1[(size_t)((c+1)*16 + wr)*64 + wcc + 4]);
            }
            #pragma unroll
            for (int kc = 0; kc < 4; ++kc) K4(acc1, AR, 20, kc, WB, 68, job, kc);
        }
        __syncthreads();
        RELU84(acc1);
        WRITE_E(acc1);                            // e1 -> EA stride 68
    }

    // ================= L2: K=64, 4 weight chunks =================
    {
        float acc2[8][4];
        INIT84(acc2, be2, job);
        float4 rw0 = GL4(We2[(size_t)wr*64 + wcc]);
        float4 rw1 = GL4(We2[(size_t)wr*64 + wcc + 4]);
        #pragma unroll 1
        for (int c = 0; c < 4; ++c) {
            __syncthreads();                      // e1 visible / prev K4 done
            STAGE_W();
            __syncthreads();
            if (c < 3) {
                rw0 = GL4(We2[(size_t)((c+1)*16 + wr)*64 + wcc]);
                rw1 = GL4(We2[(size_t)((c+1)*16 + wr)*64 + wcc + 4]);
            }
            #pragma unroll
            for (int kc = 0; kc < 4; ++kc) K4(acc2, EA, 68, c*4 + kc, WB, 68, job, kc);
        }
        __syncthreads();                          // last K4 done (EA/WB free)
        RELU84(acc2);
        WRITE_E(acc2);                            // e2 overwrites e1
        // stage W3 [64][16] -> WB (stride 16): FULL coverage, 2 rows/thread
        // (r11 bug: 4-float store on 8-stride map left cols 4-7/12-15 stale)
        {   const int r3 = t >> 2, c3 = (t & 3) * 4;
            ST4(WB + r3*16 + c3)        = GL4(We3[(size_t)r3*16 + c3]);
            ST4(WB + (r3+32)*16 + c3)   = GL4(We3[(size_t)(r3+32)*16 + c3]); }
        // stage Wd1 [16][16] -> WD1i
        if (t < 64) ST4(WD1i + (t >> 2)*16 + (t & 3)*4) =
            GL4(Wd1[(t >> 2)*16 + (t & 3)*4]);
    }
    __syncthreads();

    // ================= L3: z, K=64, 1 col/thread (col = ot) =================
    float zac[8];
    {   const float b3v = be3[ot];
        #pragma unroll
        for (int m = 0; m < 8; ++m) zac[m] = b3v; }
    #pragma unroll 2
    for (int kc = 0; kc < 16; ++kc) {
        const float w0 = sm[WB + (kc*4+0)*16 + ot];
        const float w1 = sm[WB + (kc*4+1)*16 + ot];
        const float w2 = sm[WB + (kc*4+2)*16 + ot];
        const float w3 = sm[WB + (kc*4+3)*16 + ot];
        #pragma unroll
        for (int m = 0; m < 8; ++m) {
            const float4 av = LD4(EA + (st + 8*m)*68 + kc*4);
            float s = zac[m];
            s = fmaf(av.x, w0, s); s = fmaf(av.y, w1, s);
            s = fmaf(av.z, w2, s); s = fmaf(av.w, w3, s);
            zac[m] = s;
        }
    }
    #pragma unroll
    for (int m = 0; m < 8; ++m)
        out_z[(size_t)(s0 + st + 8*m)*16 + ot] = zac[m];
    __syncthreads();              // all EA + W3 reads done
    #pragma unroll
    for (int m = 0; m < 8; ++m) sm[AR + (st + 8*m)*20 + ot] = zac[m];
    {   // stage Wd2 half0 [16][0..63] -> WB stride 68
        ST4(WB + wr*68 + wcc)     = GL4(Wd2[(size_t)wr*128 + wcc]);
        ST4(WB + wr*68 + wcc + 4) = GL4(Wd2[(size_t)wr*128 + wcc + 4]); }
    __syncthreads();

    // ======== wave 0: student-t + softmax + argmax + counts (row t<64) ======
    if (t < 64) {
        const float4 z0 = LD4(AR + t*20 + 0), z1 = LD4(AR + t*20 + 4);
        const float4 z2 = LD4(AR + t*20 + 8), z3 = LD4(AR + t*20 + 12);
        const float zz[16] = {z0.x,z0.y,z0.z,z0.w, z1.x,z1.y,z1.z,z1.w,
                              z2.x,z2.y,z2.z,z2.w, z3.x,z3.y,z3.z,z3.w};
        float d2[KC];
        #pragma unroll
        for (int k = 0; k < KC; ++k) {
            float acc = 0.f;
            #pragma unroll
            for (int l = 0; l < 16; ++l) {
                const float dl = zz[l] - centers[k*16 + l];
                acc = fmaf(dl, dl, acc);
            }
            d2[k] = acc;
        }
        float lgt[KC], ex[KC];
        float mm = -1e30f;
        #pragma unroll
        for (int k = 0; k < KC; ++k) { lgt[k] = -log1pf(d2[k]); mm = fmaxf(mm, lgt[k]); }
        float ssum = 0.f;
        #pragma unroll
        for (int k = 0; k < KC; ++k) { ex[k] = expf(lgt[k] - mm); ssum += ex[k]; }
        const float inv = 1.f / ssum;
        float4* oq = reinterpret_cast<float4*>(&out_q[(size_t)(s0 + t)*8]);
        oq[0] = make_float4(ex[0]*inv, ex[1]*inv, ex[2]*inv, ex[3]*inv);
        oq[1] = make_float4(ex[4]*inv, ex[5]*inv, ex[6]*inv, ex[7]*inv);
        int ci = 0; float best = d2[0];
        #pragma unroll
        for (int k = 1; k < KC; ++k) if (d2[k] < best) { best = d2[k]; ci = k; }
        cidx[s0 + t] = ci;
        #pragma unroll
        for (int k = 0; k < KC; ++k) {
            const u64 mk = __ballot(ci == k);
            if (t == 0 && mk) atomicAdd(&counts[k], (int)__popcll(mk));
        }
        kld[s0 + t] = 0.f;
    }

    // ================= decoder: d = relu(z Wd1 + bd1), col = ot =============
    {
        float w[16];
        #pragma unroll
        for (int k = 0; k < 16; ++k) w[k] = sm[WD1i + k*16 + ot];
        const float bb = bd1[ot];
        float dac[8];
        #pragma unroll
        for (int m = 0; m < 8; ++m) {
            const int r = st + 8*m;
            float s = bb;
            #pragma unroll
            for (int kc = 0; kc < 4; ++kc) {
                const float4 av = LD4(AR + r*20 + kc*4);
                s = fmaf(av.x, w[kc*4+0], s); s = fmaf(av.y, w[kc*4+1], s);
                s = fmaf(av.z, w[kc*4+2], s); s = fmaf(av.w, w[kc*4+3], s);
            }
            dac[m] = fmaxf(s, 0.f);
        }
        __syncthreads();          // all z reads done
        #pragma unroll
        for (int m = 0; m < 8; ++m) sm[AR + (st + 8*m)*20 + ot] = dac[m];
    }
    __syncthreads();

    // ================= xhat: K=16, N=128 (2 halves of 64) + rec =============
    float rp[8] = {0.f,0.f,0.f,0.f,0.f,0.f,0.f,0.f};
    float4 rw20 = GL4(Wd2[(size_t)wr*128 + 64 + wcc]);     // prefetch half1
    float4 rw21 = GL4(Wd2[(size_t)wr*128 + 64 + wcc + 4]);
    {
        float accx[8][4];
        INIT84(accx, bd2, job);
        #pragma unroll
        for (int kc = 0; kc < 4; ++kc) K4(accx, AR, 20, kc, WB, 68, job, kc);
        #pragma unroll
        for (int m = 0; m < 8; ++m) {
            const int r = st + 8*m;
            const float4 xa = GL4(x[(size_t)(s0+r)*128 + job]);
            float df;
            df=accx[m][0]-xa.x; rp[m]=fmaf(df,df,rp[m]);
            df=accx[m][1]-xa.y; rp[m]=fmaf(df,df,rp[m]);
            df=accx[m][2]-xa.z; rp[m]=fmaf(df,df,rp[m]);
            df=accx[m][3]-xa.w; rp[m]=fmaf(df,df,rp[m]);
            *reinterpret_cast<float4*>(&xhat[(size_t)(s0+r)*128 + job]) =
                make_float4(accx[m][0],accx[m][1],accx[m][2],accx[m][3]);
        }
    }
    __syncthreads();
    ST4(WB + wr*68 + wcc)     = rw20;
    ST4(WB + wr*68 + wcc + 4) = rw21;
    __syncthreads();
    {
        float accx[8][4];
        INIT84(accx, bd2, 64 + job);
        #pragma unroll
        for (int kc = 0; kc < 4; ++kc) K4(accx, AR, 20, kc, WB, 68, job, kc);
        #pragma unroll
        for (int m = 0; m < 8; ++m) {
            const int r = st + 8*m;
            const float4 xa = GL4(x[(size_t)(s0+r)*128 + 64 + job]);
            float df;
            df=accx[m][0]-xa.x; rp[m]=fmaf(df,df,rp[m]);
            df=accx[m][1]-xa.y; rp[m]=fmaf(df,df,rp[m]);
            df=accx[m][2]-xa.z; rp[m]=fmaf(df,df,rp[m]);
            df=accx[m][3]-xa.w; rp[m]=fmaf(df,df,rp[m]);
            *reinterpret_cast<float4*>(&xhat[(size_t)(s0+r)*128 + 64 + job]) =
                make_float4(accx[m][0],accx[m][1],accx[m][2],accx[m][3]);
        }
    }
    #pragma unroll
    for (int m = 0; m < 8; ++m) {
        float v = rp[m];
        v += __shfl_xor(v, 1); v += __shfl_xor(v, 2);
        v += __shfl_xor(v, 4); v += __shfl_xor(v, 8);
        if (ot == 0) rec[s0 + st + 8*m] = v * (1.f/128.f);
    }
}

// ---------------------------------------------------------------------------
__global__ void k_scan(const int* __restrict__ counts,
                       int* __restrict__ bases, int* __restrict__ cursors)
{
    if (threadIdx.x == 0) {
        int acc = 0;
        for (int k = 0; k < KC; ++k) { bases[k] = acc; cursors[k] = acc; acc += counts[k]; }
    }
}

__global__ __launch_bounds__(256) void k_scatter(
    const int* __restrict__ cidx, int* __restrict__ cursors, int* __restrict__ seg)
{
    const int s = blockIdx.x * 256 + threadIdx.x;
    const int lane = threadIdx.x & 63;
    const int ci = cidx[s];
    #pragma unroll
    for (int k = 0; k < KC; ++k) {
        const u64 mk = __ballot(ci == k);
        if (ci == k) {
            const int leader = __ffsll(mk) - 1;
            int base = 0;
            if (lane == leader) base = atomicAdd(&cursors[k], (int)__popcll(mk));
            base = __shfl(base, leader, 64);
            seg[base + (int)__popcll(mk & (((u64)1 << lane) - 1))] = s;
        }
    }
}

// ---------------------------------------------------------------------------
// k_heads: 64 gathered samples / 128-thread block; cluster kk block-uniform.
// ---------------------------------------------------------------------------
__global__ __launch_bounds__(128, 2) void k_heads(
    const float* __restrict__ x, const float* __restrict__ zread,
    const float* __restrict__ Wh1, const float* __restrict__ bh1,
    const float* __restrict__ Wh2, const float* __restrict__ bh2,
    const int* __restrict__ counts, const int* __restrict__ bases,
    const int* __restrict__ seg,
    float* __restrict__ surv)
{
    __shared__ float sm[SMW];
    __shared__ int idxs[64];
    const int t  = threadIdx.x;
    const int ot = t & 15, st = t >> 4;
    const int job = ot * 4;
    const int xr0 = t >> 1, xcc = (t & 1) * 8;
    const int wr  = t >> 3, wcc = (t & 7) * 8;

    int kk = -1, chunk = 0, pref = 0;
    #pragma unroll
    for (int q = 0; q < KC; ++q) {
        const int ck = (counts[q] + 63) >> 6;
        if (kk < 0) {
            if ((int)blockIdx.x < pref + ck) { kk = q; chunk = (int)blockIdx.x - pref; }
            pref += ck;
        }
    }
    if (kk < 0) return;                     // block-uniform, before any barrier
    kk    = __builtin_amdgcn_readfirstlane(kk);
    chunk = __builtin_amdgcn_readfirstlane(chunk);
    const int cnt  = __builtin_amdgcn_readfirstlane(counts[kk]);
    const int base = __builtin_amdgcn_readfirstlane(bases[kk]);

    if (t < 64) {
        const int i = chunk*64 + t;
        idxs[t] = seg[base + ((i < cnt) ? i : (cnt - 1))];
    }
    __syncthreads();
    const int irow = idxs[xr0];

    // ================= head L1: K=144 (z chunk + 8 x chunks) ================
    {
        float acc1[8][4];
        INIT84(acc1, bh1, (size_t)kk*64 + job);
        {   // stage gathered z [64][16] -> AR: BOTH 8-float halves (r11 fix)
            ST4(AR + xr0*20 + xcc)     = GL4(zread[(size_t)irow*16 + xcc]);
            ST4(AR + xr0*20 + xcc + 4) = GL4(zread[(size_t)irow*16 + xcc + 4]);
            ST4(WB + wr*68 + wcc)     = GL4(Wh1[((size_t)kk*144 + wr)*64 + wcc]);
            ST4(WB + wr*68 + wcc + 4) = GL4(Wh1[((size_t)kk*144 + wr)*64 + wcc + 4]); }
        __syncthreads();
        float4 rx0 = GL4(x[(size_t)irow*128 + xcc]);
        float4 rx1 = GL4(x[(size_t)irow*128 + xcc + 4]);
        float4 rw0 = GL4(Wh1[((size_t)kk*144 + 16 + wr)*64 + wcc]);
        float4 rw1 = GL4(Wh1[((size_t)kk*144 + 16 + wr)*64 + wcc + 4]);
        #pragma unroll
        for (int kc = 0; kc < 4; ++kc) K4(acc1, AR, 20, kc, WB, 68, job, kc);
        #pragma unroll 1
        for (int c = 0; c < 8; ++c) {
            __syncthreads();
            STAGE_X(); STAGE_W();
            __syncthreads();
            if (c < 7) {
                rx0 = GL4(x[(size_t)irow*128 + (c+1)*16 + xcc]);
                rx1 = GL4(x[(size_t)irow*128 + (c+1)*16 + xcc + 4]);
                rw0 = GL4(Wh1[((size_t)kk*144 + 16 + (c+1)*16 + wr)*64 + wcc]);
                rw1 = GL4(Wh1[((size_t)kk*144 + 16 + (c+1)*16 + wr)*64 + wcc + 4]);
            }
            #pragma unroll
            for (int kc = 0; kc < 4; ++kc) K4(acc1, AR, 20, kc, WB, 68, job, kc);
        }
        __syncthreads();
        RELU84(acc1);
        WRITE_E(acc1);            // h1 -> EA stride 68
    }

    // ================= head L2: K=64 in 4 chunks, cols padded to 64 =========
    float acc2[8][4];
    {   float4 bz;
        bz.x = (job+0 < 50) ? bh2[(size_t)kk*50 + job+0] : 0.f;
        bz.y = (job+1 < 50) ? bh2[(size_t)kk*50 + job+1] : 0.f;
        bz.z = (job+2 < 50) ? bh2[(size_t)kk*50 + job+2] : 0.f;
        bz.w = (job+3 < 50) ? bh2[(size_t)kk*50 + job+3] : 0.f;
        #pragma unroll
        for (int m = 0; m < 8; ++m) {
            acc2[m][0] = bz.x; acc2[m][1] = bz.y;
            acc2[m][2] = bz.z; acc2[m][3] = bz.w;
        } }
    float4 rv0, rv1;
    {   const size_t wrow = ((size_t)kk*64 + wr)*50;
        rv0.x = (wcc+0 < 50) ? Wh2[wrow + wcc+0] : 0.f;
        rv0.y = (wcc+1 < 50) ? Wh2[wrow + wcc+1] : 0.f;
        rv0.z = (wcc+2 < 50) ? Wh2[wrow + wcc+2] : 0.f;
        rv0.w = (wcc+3 < 50) ? Wh2[wrow + wcc+3] : 0.f;
        rv1.x = (wcc+4 < 50) ? Wh2[wrow + wcc+4] : 0.f;
        rv1.y = (wcc+5 < 50) ? Wh2[wrow + wcc+5] : 0.f;
        rv1.z = (wcc+6 < 50) ? Wh2[wrow + wcc+6] : 0.f;
        rv1.w = (wcc+7 < 50) ? Wh2[wrow + wcc+7] : 0.f; }
    #pragma unroll 1
    for (int c = 0; c < 4; ++c) {
        __syncthreads();                      // h1 visible / WB free
        ST4(WB + wr*68 + wcc)     = rv0;
        ST4(WB + wr*68 + wcc + 4) = rv1;
        __syncthreads();
        if (c < 3) {
            const size_t wrow = ((size_t)kk*64 + (c+1)*16 + wr)*50;
            rv0.x = (wcc+0 < 50) ? Wh2[wrow + wcc+0] : 0.f;
            rv0.y = (wcc+1 < 50) ? Wh2[wrow + wcc+1] : 0.f;
            rv0.z = (wcc+2 < 50) ? Wh2[wrow + wcc+2] : 0.f;
            rv0.w = (wcc+3 < 50) ? Wh2[wrow + wcc+3] : 0.f;
            rv1.x = (wcc+4 < 50) ? Wh2[wrow + wcc+4] : 0.f;
            rv1.y = (wcc+5 < 50) ? Wh2[wrow + wcc+5] : 0.f;
            rv1.z = (wcc+6 < 50) ? Wh2[wrow + wcc+6] : 0.f;
            rv1.w = (wcc+7 < 50) ? Wh2[wrow + wcc+7] : 0.f;
        }
        #pragma unroll
        for (int kc = 0; kc < 4; ++kc) K4(acc2, EA, 68, c*4 + kc, WB, 68, job, kc);
    }

    // ================= store surv (cols < 50, rows < cnt) ===================
    #pragma unroll
    for (int m = 0; m < 8; ++m) {
        const int r = st + 8*m;
        if (chunk*64 + r < cnt) {
            float* so = &surv[(size_t)idxs[r]*50 + job];   // 8B-aligned
            if (ot < 12) {
                *reinterpret_cast<float2*>(&so[0]) = make_float2(acc2[m][0], acc2[m][1]);
                *reinterpret_cast<float2*>(&so[2]) = make_float2(acc2[m][2], acc2[m][3]);
            } else if (ot == 12) {
                *reinterpret_cast<float2*>(&so[0]) = make_float2(acc2[m][0], acc2[m][1]);
            }
        }
    }
}

// ---------------------------------------------------------------------------
extern "C" void kernel_launch(void* const* d_in, const int* in_sizes, int n_in,
                              void* d_out, int out_size, void* d_ws, size_t ws_size,
                              hipStream_t stream)
{
    const float* x   = (const float*)d_in[0];
    const float* We1 = (const float*)d_in[1];
    const float* be1 = (const float*)d_in[2];
    const float* We2 = (const float*)d_in[3];
    const float* be2 = (const float*)d_in[4];
    const float* We3 = (const float*)d_in[5];
    const float* be3 = (const float*)d_in[6];
    const float* Wd1 = (const float*)d_in[7];
    const float* bd1 = (const float*)d_in[8];
    const float* Wd2 = (const float*)d_in[9];
    const float* bd2 = (const float*)d_in[10];
    const float* Wh1 = (const float*)d_in[11];
    const float* bh1 = (const float*)d_in[12];
    const float* Wh2 = (const float*)d_in[13];
    const float* bh2 = (const float*)d_in[14];
    const float* cen = (const float*)d_in[15];
    float* out = (float*)d_out;

    float* out_z  = out;
    float* out_q  = out + (size_t)NS * 16;
    float* out_sv = out + (size_t)NS * 24;
    float* out_xh = out + (size_t)NS * 74;
    float* out_rc = out + (size_t)NS * 202;
    float* out_kl = out + (size_t)NS * 203;

    int* cidx    = (int*)d_ws;       // [NS]
    int* counts  = cidx + NS;        // [8]
    int* bases   = counts + KC;      // [8]
    int* cursors = bases + KC;       // [8]
    int* seg     = cursors + KC;     // [NS]

    hipMemsetAsync(counts, 0, KC * sizeof(int), stream);

    k_enc<<<dim3(NS / 64), dim3(128), 0, stream>>>(
        x, We1, be1, We2, be2, We3, be3, Wd1, bd1, Wd2, bd2, cen,
        out_z, out_q, out_xh, out_rc, out_kl, cidx, counts);

    k_scan<<<dim3(1), dim3(64), 0, stream>>>(counts, bases, cursors);

    k_scatter<<<dim3(NS / 256), dim3(256), 0, stream>>>(cidx, cursors, seg);

    k_heads<<<dim3(NS / 64 + KC), dim3(128), 0, stream>>>(
        x, out_z, Wh1, bh1, Wh2, bh2, counts, bases, seg, out_sv);
}